// Round 1
// baseline (947.856 us; speedup 1.0000x reference)
//
#include <hip/hip_runtime.h>
#include <math.h>

#define H 1024
#define MTOK 65536          // B*S*L = 4*2048*8
#define TM 128
#define BK 64
#define LDApad 72           // padded LDS row length (elems)

typedef __attribute__((ext_vector_type(8))) short short8;
typedef __attribute__((ext_vector_type(4))) short short4v;
typedef __attribute__((ext_vector_type(4))) float f32x4;

union frag_u { short8 s8; struct { short4v lo, hi; } p; };

// ---------------- ws layout (bytes) ----------------
#define WS_R_OFF   0                          // 64 floats
#define WS_BS_OFF  256                        // 8 floats
#define WS_WR_OFF  4096                       // bf16 1024*1024   (2 MB)
#define WS_WG_OFF  (4096 + 2*1024*1024)       // bf16 1024*2048   (4 MB)
#define WS_RT_OFF  (8*1024*1024)              // bf16 MTOK*1024   (128 MB)

static __device__ __forceinline__ unsigned short f2bf(float f) {
    unsigned int u = __float_as_uint(f);
    u = u + 0x7fffu + ((u >> 16) & 1u);       // RNE
    return (unsigned short)(u >> 16);
}
static __device__ __forceinline__ float bf2f(unsigned short s) {
    return __uint_as_float(((unsigned int)s) << 16);
}

// ---------------- routing matrix ----------------
__global__ void k_routing(const float* __restrict__ lp, const float* __restrict__ thr,
                          float* __restrict__ wsR, float* __restrict__ wsBS) {
    int t = threadIdx.x;            // 0..63
    int i = t >> 3, j = t & 7;
    float mx = 0.5f * (lp[i*3+0] + lp[j*3+0]);
    float my = 0.5f * (lp[i*3+1] + lp[j*3+1]);
    float mz = 0.5f * (lp[i*3+2] + lp[j*3+2]);
    float f = sinf(mx)*cosf(my) + sinf(my)*cosf(mz) + sinf(mz)*cosf(mx) - thr[0];
    float r = 1.0f / (1.0f + expf(-2.0f * f));
    if (i == j) r = 1.0f;
    float s = r;
    s += __shfl_xor(s, 1, 64);
    s += __shfl_xor(s, 2, 64);
    s += __shfl_xor(s, 4, 64);
    float R = r / (s + 1e-6f);
    wsR[t] = R;
    if (j == 0) wsBS[i] = s / (s + 1e-6f);
}

// ---------------- fp32 -> bf16 convert ----------------
__global__ void k_f32_to_bf16(const float* __restrict__ src, unsigned short* __restrict__ dst, int n4) {
    int i = blockIdx.x * blockDim.x + threadIdx.x;
    int stride = gridDim.x * blockDim.x;
    for (; i < n4; i += stride) {
        float4 v = reinterpret_cast<const float4*>(src)[i];
        ushort4 o = make_ushort4(f2bf(v.x), f2bf(v.y), f2bf(v.z), f2bf(v.w));
        reinterpret_cast<ushort4*>(dst)[i] = o;
    }
}

// ---------------- pass 1: routed = mix(x @ Wr^T) + scale*b ----------------
__global__ __launch_bounds__(256) void k_pass1(
    const float* __restrict__ x,            // [MTOK][H] fp32
    const unsigned short* __restrict__ Wr,  // [H][H] bf16 (row=out e, col=k)
    const float* __restrict__ b_route,      // [H]
    const float* __restrict__ wsR,          // [64]
    const float* __restrict__ wsBS,         // [8]
    unsigned short* __restrict__ routed)    // [MTOK][H] bf16
{
    __shared__ unsigned short As[TM][LDApad];
    __shared__ unsigned short Bs[TM][LDApad];
    __shared__ float Rs[64];
    __shared__ float BSs[8];

    const int tid = threadIdx.x;
    const int bm = blockIdx.x >> 3;
    const int bn = blockIdx.x & 7;
    const int m0 = bm * TM;
    const int n0 = bn * TM;

    if (tid < 64) Rs[tid] = wsR[tid];
    if (tid < 8)  BSs[tid] = wsBS[tid];

    const int wid  = tid >> 6;
    const int lane = tid & 63;
    const int wm = (wid >> 1) * 64;
    const int wn = (wid & 1) * 64;
    const int lr = lane & 15;
    const int kq = lane >> 4;

    f32x4 acc[4][4];
#pragma unroll
    for (int i = 0; i < 4; i++)
#pragma unroll
        for (int j = 0; j < 4; j++) acc[i][j] = (f32x4)0.0f;

    for (int kt = 0; kt < H / BK; ++kt) {
        const int k0 = kt * BK;
        // stage A (x fp32 -> bf16 in LDS)
#pragma unroll
        for (int it = 0; it < 4; ++it) {
            int slot = it * 256 + tid;
            int r = slot >> 3, c8 = (slot & 7) * 8;
            const float* src = x + (size_t)(m0 + r) * H + k0 + c8;
            float4 v0 = *reinterpret_cast<const float4*>(src);
            float4 v1 = *reinterpret_cast<const float4*>(src + 4);
            short4v w0, w1;
            w0[0]=(short)f2bf(v0.x); w0[1]=(short)f2bf(v0.y); w0[2]=(short)f2bf(v0.z); w0[3]=(short)f2bf(v0.w);
            w1[0]=(short)f2bf(v1.x); w1[1]=(short)f2bf(v1.y); w1[2]=(short)f2bf(v1.z); w1[3]=(short)f2bf(v1.w);
            *reinterpret_cast<short4v*>(&As[r][c8])     = w0;
            *reinterpret_cast<short4v*>(&As[r][c8 + 4]) = w1;
        }
        // stage B (Wr bf16, rows = output channel n, contiguous k)
#pragma unroll
        for (int it = 0; it < 4; ++it) {
            int slot = it * 256 + tid;
            int r = slot >> 3, c8 = (slot & 7) * 8;
            const unsigned short* src = Wr + (size_t)(n0 + r) * H + k0 + c8;
            uint4 v = *reinterpret_cast<const uint4*>(src);
            *reinterpret_cast<uint2*>(&Bs[r][c8])     = make_uint2(v.x, v.y);
            *reinterpret_cast<uint2*>(&Bs[r][c8 + 4]) = make_uint2(v.z, v.w);
        }
        __syncthreads();
#pragma unroll
        for (int ks = 0; ks < BK; ks += 32) {
            short8 a[4], b[4];
#pragma unroll
            for (int i = 0; i < 4; i++) {
                frag_u fa;
                const unsigned short* pa = &As[wm + i*16 + lr][ks + kq*8];
                fa.p.lo = *reinterpret_cast<const short4v*>(pa);
                fa.p.hi = *reinterpret_cast<const short4v*>(pa + 4);
                a[i] = fa.s8;
            }
#pragma unroll
            for (int j = 0; j < 4; j++) {
                frag_u fb;
                const unsigned short* pb = &Bs[wn + j*16 + lr][ks + kq*8];
                fb.p.lo = *reinterpret_cast<const short4v*>(pb);
                fb.p.hi = *reinterpret_cast<const short4v*>(pb + 4);
                b[j] = fb.s8;
            }
#pragma unroll
            for (int i = 0; i < 4; i++)
#pragma unroll
                for (int j = 0; j < 4; j++)
                    acc[i][j] = __builtin_amdgcn_mfma_f32_16x16x32_bf16(a[i], b[j], acc[i][j], 0, 0, 0);
        }
        __syncthreads();
    }

    // epilogue: limb mix (group of 8 rows) + bias, store bf16
    const int lowbit = kq & 1;
    float rc[4][8];
#pragma unroll
    for (int e = 0; e < 4; e++)
#pragma unroll
        for (int jj = 0; jj < 8; jj++) rc[e][jj] = Rs[(lowbit*4 + e)*8 + jj];
    float bsc[4];
#pragma unroll
    for (int e = 0; e < 4; e++) bsc[e] = BSs[lowbit*4 + e];

#pragma unroll
    for (int i = 0; i < 4; i++) {
        int gmBase = m0 + wm + i*16 + kq*4;
#pragma unroll
        for (int j2 = 0; j2 < 4; j2++) {
            int gn = n0 + wn + j2*16 + lr;
            float br = b_route[gn];
            float own[4], oth[4];
#pragma unroll
            for (int e = 0; e < 4; e++) {
                own[e] = acc[i][j2][e];
                oth[e] = __shfl_xor(own[e], 16, 64);
            }
            float g8[8];
#pragma unroll
            for (int e = 0; e < 4; e++) {
                if (lowbit == 0) { g8[e] = own[e]; g8[4+e] = oth[e]; }
                else             { g8[e] = oth[e]; g8[4+e] = own[e]; }
            }
#pragma unroll
            for (int e = 0; e < 4; e++) {
                float m = 0.0f;
#pragma unroll
                for (int jj = 0; jj < 8; jj++) m += rc[e][jj] * g8[jj];
                m += bsc[e] * br;
                routed[(size_t)(gmBase + e) * H + gn] = f2bf(m);
            }
        }
    }
}

// ---------------- pass 2: out = g*routed + (1-g)*x, g = sigmoid([x|routed] @ Wg^T + b) ----------------
__global__ __launch_bounds__(256) void k_pass2(
    const float* __restrict__ x,
    const unsigned short* __restrict__ Wg,  // [H][2H] bf16
    const float* __restrict__ b_gate,
    const unsigned short* __restrict__ routed,
    float* __restrict__ out)
{
    __shared__ unsigned short As[TM][LDApad];
    __shared__ unsigned short Bs[TM][LDApad];

    const int tid = threadIdx.x;
    const int bm = blockIdx.x >> 3;
    const int bn = blockIdx.x & 7;
    const int m0 = bm * TM;
    const int n0 = bn * TM;

    const int wid  = tid >> 6;
    const int lane = tid & 63;
    const int wm = (wid >> 1) * 64;
    const int wn = (wid & 1) * 64;
    const int lr = lane & 15;
    const int kq = lane >> 4;

    f32x4 acc[4][4];
#pragma unroll
    for (int i = 0; i < 4; i++)
#pragma unroll
        for (int j = 0; j < 4; j++) acc[i][j] = (f32x4)0.0f;

    for (int kt = 0; kt < (2 * H) / BK; ++kt) {
        const int k0 = kt * BK;
        if (kt < H / BK) {
            // A from x (fp32 -> bf16)
#pragma unroll
            for (int it = 0; it < 4; ++it) {
                int slot = it * 256 + tid;
                int r = slot >> 3, c8 = (slot & 7) * 8;
                const float* src = x + (size_t)(m0 + r) * H + k0 + c8;
                float4 v0 = *reinterpret_cast<const float4*>(src);
                float4 v1 = *reinterpret_cast<const float4*>(src + 4);
                short4v w0, w1;
                w0[0]=(short)f2bf(v0.x); w0[1]=(short)f2bf(v0.y); w0[2]=(short)f2bf(v0.z); w0[3]=(short)f2bf(v0.w);
                w1[0]=(short)f2bf(v1.x); w1[1]=(short)f2bf(v1.y); w1[2]=(short)f2bf(v1.z); w1[3]=(short)f2bf(v1.w);
                *reinterpret_cast<short4v*>(&As[r][c8])     = w0;
                *reinterpret_cast<short4v*>(&As[r][c8 + 4]) = w1;
            }
        } else {
            // A from routed (bf16 ws)
#pragma unroll
            for (int it = 0; it < 4; ++it) {
                int slot = it * 256 + tid;
                int r = slot >> 3, c8 = (slot & 7) * 8;
                const unsigned short* src = routed + (size_t)(m0 + r) * H + (k0 - H) + c8;
                uint4 v = *reinterpret_cast<const uint4*>(src);
                *reinterpret_cast<uint2*>(&As[r][c8])     = make_uint2(v.x, v.y);
                *reinterpret_cast<uint2*>(&As[r][c8 + 4]) = make_uint2(v.z, v.w);
            }
        }
        // B from Wg
#pragma unroll
        for (int it = 0; it < 4; ++it) {
            int slot = it * 256 + tid;
            int r = slot >> 3, c8 = (slot & 7) * 8;
            const unsigned short* src = Wg + (size_t)(n0 + r) * (2 * H) + k0 + c8;
            uint4 v = *reinterpret_cast<const uint4*>(src);
            *reinterpret_cast<uint2*>(&Bs[r][c8])     = make_uint2(v.x, v.y);
            *reinterpret_cast<uint2*>(&Bs[r][c8 + 4]) = make_uint2(v.z, v.w);
        }
        __syncthreads();
#pragma unroll
        for (int ks = 0; ks < BK; ks += 32) {
            short8 a[4], b[4];
#pragma unroll
            for (int i = 0; i < 4; i++) {
                frag_u fa;
                const unsigned short* pa = &As[wm + i*16 + lr][ks + kq*8];
                fa.p.lo = *reinterpret_cast<const short4v*>(pa);
                fa.p.hi = *reinterpret_cast<const short4v*>(pa + 4);
                a[i] = fa.s8;
            }
#pragma unroll
            for (int j = 0; j < 4; j++) {
                frag_u fb;
                const unsigned short* pb = &Bs[wn + j*16 + lr][ks + kq*8];
                fb.p.lo = *reinterpret_cast<const short4v*>(pb);
                fb.p.hi = *reinterpret_cast<const short4v*>(pb + 4);
                b[j] = fb.s8;
            }
#pragma unroll
            for (int i = 0; i < 4; i++)
#pragma unroll
                for (int j = 0; j < 4; j++)
                    acc[i][j] = __builtin_amdgcn_mfma_f32_16x16x32_bf16(a[i], b[j], acc[i][j], 0, 0, 0);
        }
        __syncthreads();
    }

    // epilogue: sigmoid gate + blend (fp32 x re-read for accuracy)
#pragma unroll
    for (int i = 0; i < 4; i++) {
        int gmBase = m0 + wm + i*16 + kq*4;
#pragma unroll
        for (int j2 = 0; j2 < 4; j2++) {
            int gn = n0 + wn + j2*16 + lr;
            float bg = b_gate[gn];
#pragma unroll
            for (int e = 0; e < 4; e++) {
                size_t idx = (size_t)(gmBase + e) * H + gn;
                float t = acc[i][j2][e] + bg;
                float g = 1.0f / (1.0f + expf(-t));
                float rt = bf2f(routed[idx]);
                float xv = x[idx];
                out[idx] = g * rt + (1.0f - g) * xv;
            }
        }
    }
}

// ---------------- fallback (small ws): fully fused, fp32 vector ----------------
__global__ __launch_bounds__(256) void k_fallback(
    const float* __restrict__ x, const float* __restrict__ Wr, const float* __restrict__ br,
    const float* __restrict__ Wg, const float* __restrict__ bg,
    const float* __restrict__ wsR, const float* __restrict__ wsBS,
    float* __restrict__ out)
{
    __shared__ float xs[8][H];
    __shared__ float rt[8][H];
    __shared__ float Rs[64];
    __shared__ float BSs[8];

    const int tid = threadIdx.x;
    const size_t base = (size_t)blockIdx.x * (8 * H);
    if (tid < 64) Rs[tid] = wsR[tid];
    if (tid < 8)  BSs[tid] = wsBS[tid];

#pragma unroll
    for (int it = 0; it < 8; ++it) {
        int s = it * 256 + tid;
        reinterpret_cast<float4*>(&xs[0][0])[s] = reinterpret_cast<const float4*>(x + base)[s];
    }
    __syncthreads();

    for (int eo = 0; eo < 4; ++eo) {
        int e = eo * 256 + tid;
        float acc[8];
#pragma unroll
        for (int l = 0; l < 8; l++) acc[l] = 0.0f;
        const float* w = Wr + (size_t)e * H;
        for (int k = 0; k < H; k += 4) {
            float4 wv = *reinterpret_cast<const float4*>(w + k);
#pragma unroll
            for (int l = 0; l < 8; l++)
                acc[l] += wv.x * xs[l][k] + wv.y * xs[l][k+1] + wv.z * xs[l][k+2] + wv.w * xs[l][k+3];
        }
        float brv = br[e];
#pragma unroll
        for (int l = 0; l < 8; l++) {
            float m = 0.0f;
#pragma unroll
            for (int j = 0; j < 8; j++) m += Rs[l*8 + j] * acc[j];
            rt[l][e] = m + BSs[l] * brv;
        }
    }
    __syncthreads();

    for (int eo = 0; eo < 4; ++eo) {
        int e = eo * 256 + tid;
        float acc2[8];
#pragma unroll
        for (int l = 0; l < 8; l++) acc2[l] = 0.0f;
        const float* w1 = Wg + (size_t)e * (2 * H);
        for (int k = 0; k < H; k += 4) {
            float4 wv = *reinterpret_cast<const float4*>(w1 + k);
#pragma unroll
            for (int l = 0; l < 8; l++)
                acc2[l] += wv.x * xs[l][k] + wv.y * xs[l][k+1] + wv.z * xs[l][k+2] + wv.w * xs[l][k+3];
        }
        const float* w2 = w1 + H;
        for (int k = 0; k < H; k += 4) {
            float4 wv = *reinterpret_cast<const float4*>(w2 + k);
#pragma unroll
            for (int l = 0; l < 8; l++)
                acc2[l] += wv.x * rt[l][k] + wv.y * rt[l][k+1] + wv.z * rt[l][k+2] + wv.w * rt[l][k+3];
        }
        float bgv = bg[e];
#pragma unroll
        for (int l = 0; l < 8; l++) {
            float t = acc2[l] + bgv;
            float g = 1.0f / (1.0f + expf(-t));
            out[base + (size_t)l * H + e] = g * rt[l][e] + (1.0f - g) * xs[l][e];
        }
    }
}

extern "C" void kernel_launch(void* const* d_in, const int* in_sizes, int n_in,
                              void* d_out, int out_size, void* d_ws, size_t ws_size,
                              hipStream_t stream) {
    const float* x   = (const float*)d_in[0];
    const float* lp  = (const float*)d_in[1];
    const float* thr = (const float*)d_in[2];
    const float* Wr  = (const float*)d_in[3];
    const float* br  = (const float*)d_in[4];
    const float* Wg  = (const float*)d_in[5];
    const float* bg  = (const float*)d_in[6];
    float* out = (float*)d_out;
    char* ws = (char*)d_ws;

    float* wsR  = (float*)(ws + WS_R_OFF);
    float* wsBS = (float*)(ws + WS_BS_OFF);

    k_routing<<<1, 64, 0, stream>>>(lp, thr, wsR, wsBS);

    const size_t need = (size_t)WS_RT_OFF + (size_t)MTOK * H * 2;
    if (ws_size >= need) {
        unsigned short* wsWr = (unsigned short*)(ws + WS_WR_OFF);
        unsigned short* wsWg = (unsigned short*)(ws + WS_WG_OFF);
        unsigned short* wsRt = (unsigned short*)(ws + WS_RT_OFF);
        k_f32_to_bf16<<<512, 256, 0, stream>>>(Wr, wsWr, (1024 * 1024) / 4);
        k_f32_to_bf16<<<1024, 256, 0, stream>>>(Wg, wsWg, (1024 * 2048) / 4);
        k_pass1<<<(MTOK / TM) * (H / TM), 256, 0, stream>>>(x, wsWr, br, wsR, wsBS, wsRt);
        k_pass2<<<(MTOK / TM) * (H / TM), 256, 0, stream>>>(x, wsWg, bg, wsRt, out);
    } else {
        k_fallback<<<MTOK / 8, 256, 0, stream>>>(x, Wr, br, Wg, bg, wsR, wsBS, out);
    }
}

// Round 2
// 850.425 us; speedup vs baseline: 1.1146x; 1.1146x over previous
//
#include <hip/hip_runtime.h>
#include <math.h>

#define H 1024
#define H2 2048
#define MTOK 65536          // B*S*L = 4*2048*8
#define TM 128
#define BK 64
#define LDApad 72           // padded LDS row length (elems) -- mid-tier kernels only

typedef __attribute__((ext_vector_type(8))) short short8;
typedef __attribute__((ext_vector_type(4))) short short4v;
typedef __attribute__((ext_vector_type(4))) float f32x4;

union frag_u { short8 s8; struct { short4v lo, hi; } p; };

// ---------------- ws layout (bytes) ----------------
#define WS_R_OFF   0                          // 64 floats
#define WS_BS_OFF  256                        // 8 floats
#define WS_WR_OFF  4096                       // bf16 1024*1024   (2 MB)
#define WS_WG_OFF  (4096 + 2*1024*1024)       // bf16 1024*2048   (4 MB)
#define WS_RT_OFF  (8ull*1024*1024)           // bf16 MTOK*1024   (128 MB)
#define WS_XB_OFF  (WS_RT_OFF + (size_t)MTOK*H*2)   // bf16 MTOK*1024 (128 MB)
#define WS_NEED_FULL (WS_XB_OFF + (size_t)MTOK*H*2)
#define WS_NEED_MID  (WS_RT_OFF + (size_t)MTOK*H*2)

static __device__ __forceinline__ unsigned short f2bf(float f) {
    unsigned int u = __float_as_uint(f);
    u = u + 0x7fffu + ((u >> 16) & 1u);       // RNE
    return (unsigned short)(u >> 16);
}
static __device__ __forceinline__ float bf2f(unsigned short s) {
    return __uint_as_float(((unsigned int)s) << 16);
}

static __device__ __forceinline__ void gload16(const void* g, void* l) {
    __builtin_amdgcn_global_load_lds(
        (const __attribute__((address_space(1))) void*)g,
        (__attribute__((address_space(3))) void*)l, 16, 0, 0);
}

// ---------------- routing matrix ----------------
__global__ void k_routing(const float* __restrict__ lp, const float* __restrict__ thr,
                          float* __restrict__ wsR, float* __restrict__ wsBS) {
    int t = threadIdx.x;            // 0..63
    int i = t >> 3, j = t & 7;
    float mx = 0.5f * (lp[i*3+0] + lp[j*3+0]);
    float my = 0.5f * (lp[i*3+1] + lp[j*3+1]);
    float mz = 0.5f * (lp[i*3+2] + lp[j*3+2]);
    float f = sinf(mx)*cosf(my) + sinf(my)*cosf(mz) + sinf(mz)*cosf(mx) - thr[0];
    float r = 1.0f / (1.0f + expf(-2.0f * f));
    if (i == j) r = 1.0f;
    float s = r;
    s += __shfl_xor(s, 1, 64);
    s += __shfl_xor(s, 2, 64);
    s += __shfl_xor(s, 4, 64);
    float R = r / (s + 1e-6f);
    wsR[t] = R;
    if (j == 0) wsBS[i] = s / (s + 1e-6f);
}

// ---------------- fp32 -> bf16 convert ----------------
__global__ void k_f32_to_bf16(const float* __restrict__ src, unsigned short* __restrict__ dst, int n4) {
    int i = blockIdx.x * blockDim.x + threadIdx.x;
    int stride = gridDim.x * blockDim.x;
    for (; i < n4; i += stride) {
        float4 v = reinterpret_cast<const float4*>(src)[i];
        ushort4 o = make_ushort4(f2bf(v.x), f2bf(v.y), f2bf(v.z), f2bf(v.w));
        reinterpret_cast<ushort4*>(dst)[i] = o;
    }
}

// =====================================================================
// FAST TIER: all-bf16 GEMMs, m97 structure (global_load_lds w=16, linear LDS)
// =====================================================================

// pass 1: routed = mix(xb @ Wr^T) + scale*b   (all-bf16 operands)
__global__ __launch_bounds__(256) void k_p1b(
    const unsigned short* __restrict__ xb,   // [MTOK][H] bf16
    const unsigned short* __restrict__ Wr,   // [H][H] bf16
    const float* __restrict__ b_route,
    const float* __restrict__ wsR, const float* __restrict__ wsBS,
    unsigned short* __restrict__ routed)
{
    __shared__ unsigned short As[TM * BK];   // linear [128][64]
    __shared__ unsigned short Bs[TM * BK];
    __shared__ float Rs[64];
    __shared__ float BSs[8];

    const int tid = threadIdx.x;
    // XCD-chunked bijective swizzle: nwg=4096, 512 per XCD
    const int l = (blockIdx.x & 7) * 512 + (blockIdx.x >> 3);
    const int bm = l >> 3;
    const int bn = l & 7;
    const int m0 = bm * TM;
    const int n0 = bn * TM;

    if (tid < 64) Rs[tid] = wsR[tid];
    if (tid < 8)  BSs[tid] = wsBS[tid];

    const int wid  = tid >> 6;
    const int lane = tid & 63;
    const int wm = (wid >> 1) * 64;
    const int wn = (wid & 1) * 64;
    const int lr = lane & 15;
    const int kq = lane >> 4;

    f32x4 acc[4][4];
#pragma unroll
    for (int i = 0; i < 4; i++)
#pragma unroll
        for (int j = 0; j < 4; j++) acc[i][j] = (f32x4)0.0f;

    for (int kt = 0; kt < H / BK; ++kt) {
        const int k0 = kt * BK;
#pragma unroll
        for (int it = 0; it < 4; ++it) {
            const int sb = it * 4 + wid;         // 0..15, wave-uniform
            const int slot = sb * 64 + lane;
            const int row = slot >> 3, c8 = (slot & 7) * 8;
            gload16(xb + (size_t)(m0 + row) * H + k0 + c8, &As[sb * 512]);
            gload16(Wr + (size_t)(n0 + row) * H + k0 + c8, &Bs[sb * 512]);
        }
        __syncthreads();
#pragma unroll
        for (int ks = 0; ks < BK; ks += 32) {
            short8 a[4], b[4];
#pragma unroll
            for (int i = 0; i < 4; i++)
                a[i] = *reinterpret_cast<const short8*>(&As[(wm + i*16 + lr) * BK + ks + kq*8]);
#pragma unroll
            for (int j = 0; j < 4; j++)
                b[j] = *reinterpret_cast<const short8*>(&Bs[(wn + j*16 + lr) * BK + ks + kq*8]);
#pragma unroll
            for (int i = 0; i < 4; i++)
#pragma unroll
                for (int j = 0; j < 4; j++)
                    acc[i][j] = __builtin_amdgcn_mfma_f32_16x16x32_bf16(a[i], b[j], acc[i][j], 0, 0, 0);
        }
        __syncthreads();
    }

    // epilogue: limb mix (rows grouped by 8) + bias, store bf16
    const int lowbit = kq & 1;
    float rc[4][8];
#pragma unroll
    for (int e = 0; e < 4; e++)
#pragma unroll
        for (int jj = 0; jj < 8; jj++) rc[e][jj] = Rs[(lowbit*4 + e)*8 + jj];
    float bsc[4];
#pragma unroll
    for (int e = 0; e < 4; e++) bsc[e] = BSs[lowbit*4 + e];

#pragma unroll
    for (int i = 0; i < 4; i++) {
        int gmBase = m0 + wm + i*16 + kq*4;
#pragma unroll
        for (int j2 = 0; j2 < 4; j2++) {
            int gn = n0 + wn + j2*16 + lr;
            float br = b_route[gn];
            float own[4], oth[4];
#pragma unroll
            for (int e = 0; e < 4; e++) {
                own[e] = acc[i][j2][e];
                oth[e] = __shfl_xor(own[e], 16, 64);
            }
            float g8[8];
#pragma unroll
            for (int e = 0; e < 4; e++) {
                if (lowbit == 0) { g8[e] = own[e]; g8[4+e] = oth[e]; }
                else             { g8[e] = oth[e]; g8[4+e] = own[e]; }
            }
#pragma unroll
            for (int e = 0; e < 4; e++) {
                float m = 0.0f;
#pragma unroll
                for (int jj = 0; jj < 8; jj++) m += rc[e][jj] * g8[jj];
                m += bsc[e] * br;
                routed[(size_t)(gmBase + e) * H + gn] = f2bf(m);
            }
        }
    }
}

// pass 2: out = g*routed + (1-g)*x,  g = sigmoid([xb|routed] @ Wg^T + b)
__global__ __launch_bounds__(256) void k_p2b(
    const unsigned short* __restrict__ xb,     // [MTOK][H] bf16
    const unsigned short* __restrict__ Wg,     // [H][2H] bf16
    const float* __restrict__ b_gate,
    const unsigned short* __restrict__ routed, // [MTOK][H] bf16
    float* __restrict__ out)
{
    __shared__ unsigned short As[TM * BK];
    __shared__ unsigned short Bs[TM * BK];

    const int tid = threadIdx.x;
    const int l = (blockIdx.x & 7) * 512 + (blockIdx.x >> 3);
    const int bm = l >> 3;
    const int bn = l & 7;
    const int m0 = bm * TM;
    const int n0 = bn * TM;

    const int wid  = tid >> 6;
    const int lane = tid & 63;
    const int wm = (wid >> 1) * 64;
    const int wn = (wid & 1) * 64;
    const int lr = lane & 15;
    const int kq = lane >> 4;

    f32x4 acc[4][4];
#pragma unroll
    for (int i = 0; i < 4; i++)
#pragma unroll
        for (int j = 0; j < 4; j++) acc[i][j] = (f32x4)0.0f;

    for (int kt = 0; kt < H2 / BK; ++kt) {
        const int k0 = kt * BK;
        const unsigned short* Asrc = (k0 < H) ? (xb + k0) : (routed + (k0 - H));
#pragma unroll
        for (int it = 0; it < 4; ++it) {
            const int sb = it * 4 + wid;
            const int slot = sb * 64 + lane;
            const int row = slot >> 3, c8 = (slot & 7) * 8;
            gload16(Asrc + (size_t)(m0 + row) * H + c8, &As[sb * 512]);
            gload16(Wg + (size_t)(n0 + row) * H2 + k0 + c8, &Bs[sb * 512]);
        }
        __syncthreads();
#pragma unroll
        for (int ks = 0; ks < BK; ks += 32) {
            short8 a[4], b[4];
#pragma unroll
            for (int i = 0; i < 4; i++)
                a[i] = *reinterpret_cast<const short8*>(&As[(wm + i*16 + lr) * BK + ks + kq*8]);
#pragma unroll
            for (int j = 0; j < 4; j++)
                b[j] = *reinterpret_cast<const short8*>(&Bs[(wn + j*16 + lr) * BK + ks + kq*8]);
#pragma unroll
            for (int i = 0; i < 4; i++)
#pragma unroll
                for (int j = 0; j < 4; j++)
                    acc[i][j] = __builtin_amdgcn_mfma_f32_16x16x32_bf16(a[i], b[j], acc[i][j], 0, 0, 0);
        }
        __syncthreads();
    }

    // epilogue: sigmoid gate + blend (bf16 x for blend -- error budget ok)
#pragma unroll
    for (int i = 0; i < 4; i++) {
        int gmBase = m0 + wm + i*16 + kq*4;
#pragma unroll
        for (int j2 = 0; j2 < 4; j2++) {
            int gn = n0 + wn + j2*16 + lr;
            float bg = b_gate[gn];
#pragma unroll
            for (int e = 0; e < 4; e++) {
                size_t idx = (size_t)(gmBase + e) * H + gn;
                float t = acc[i][j2][e] + bg;
                float g = 1.0f / (1.0f + expf(-t));
                float rt = bf2f(routed[idx]);
                float xv = bf2f(xb[idx]);
                out[idx] = g * rt + (1.0f - g) * xv;
            }
        }
    }
}

// =====================================================================
// MID TIER (ws >= 136 MB): Round-1 kernels (fp32 x staged+converted inline)
// =====================================================================

__global__ __launch_bounds__(256) void k_pass1(
    const float* __restrict__ x,
    const unsigned short* __restrict__ Wr,
    const float* __restrict__ b_route,
    const float* __restrict__ wsR,
    const float* __restrict__ wsBS,
    unsigned short* __restrict__ routed)
{
    __shared__ unsigned short As[TM][LDApad];
    __shared__ unsigned short Bs[TM][LDApad];
    __shared__ float Rs[64];
    __shared__ float BSs[8];

    const int tid = threadIdx.x;
    const int bm = blockIdx.x >> 3;
    const int bn = blockIdx.x & 7;
    const int m0 = bm * TM;
    const int n0 = bn * TM;

    if (tid < 64) Rs[tid] = wsR[tid];
    if (tid < 8)  BSs[tid] = wsBS[tid];

    const int wid  = tid >> 6;
    const int lane = tid & 63;
    const int wm = (wid >> 1) * 64;
    const int wn = (wid & 1) * 64;
    const int lr = lane & 15;
    const int kq = lane >> 4;

    f32x4 acc[4][4];
#pragma unroll
    for (int i = 0; i < 4; i++)
#pragma unroll
        for (int j = 0; j < 4; j++) acc[i][j] = (f32x4)0.0f;

    for (int kt = 0; kt < H / BK; ++kt) {
        const int k0 = kt * BK;
#pragma unroll
        for (int it = 0; it < 4; ++it) {
            int slot = it * 256 + tid;
            int r = slot >> 3, c8 = (slot & 7) * 8;
            const float* src = x + (size_t)(m0 + r) * H + k0 + c8;
            float4 v0 = *reinterpret_cast<const float4*>(src);
            float4 v1 = *reinterpret_cast<const float4*>(src + 4);
            short4v w0, w1;
            w0[0]=(short)f2bf(v0.x); w0[1]=(short)f2bf(v0.y); w0[2]=(short)f2bf(v0.z); w0[3]=(short)f2bf(v0.w);
            w1[0]=(short)f2bf(v1.x); w1[1]=(short)f2bf(v1.y); w1[2]=(short)f2bf(v1.z); w1[3]=(short)f2bf(v1.w);
            *reinterpret_cast<short4v*>(&As[r][c8])     = w0;
            *reinterpret_cast<short4v*>(&As[r][c8 + 4]) = w1;
        }
#pragma unroll
        for (int it = 0; it < 4; ++it) {
            int slot = it * 256 + tid;
            int r = slot >> 3, c8 = (slot & 7) * 8;
            const unsigned short* src = Wr + (size_t)(n0 + r) * H + k0 + c8;
            uint4 v = *reinterpret_cast<const uint4*>(src);
            *reinterpret_cast<uint2*>(&Bs[r][c8])     = make_uint2(v.x, v.y);
            *reinterpret_cast<uint2*>(&Bs[r][c8 + 4]) = make_uint2(v.z, v.w);
        }
        __syncthreads();
#pragma unroll
        for (int ks = 0; ks < BK; ks += 32) {
            short8 a[4], b[4];
#pragma unroll
            for (int i = 0; i < 4; i++) {
                frag_u fa;
                const unsigned short* pa = &As[wm + i*16 + lr][ks + kq*8];
                fa.p.lo = *reinterpret_cast<const short4v*>(pa);
                fa.p.hi = *reinterpret_cast<const short4v*>(pa + 4);
                a[i] = fa.s8;
            }
#pragma unroll
            for (int j = 0; j < 4; j++) {
                frag_u fb;
                const unsigned short* pb = &Bs[wn + j*16 + lr][ks + kq*8];
                fb.p.lo = *reinterpret_cast<const short4v*>(pb);
                fb.p.hi = *reinterpret_cast<const short4v*>(pb + 4);
                b[j] = fb.s8;
            }
#pragma unroll
            for (int i = 0; i < 4; i++)
#pragma unroll
                for (int j = 0; j < 4; j++)
                    acc[i][j] = __builtin_amdgcn_mfma_f32_16x16x32_bf16(a[i], b[j], acc[i][j], 0, 0, 0);
        }
        __syncthreads();
    }

    const int lowbit = kq & 1;
    float rc[4][8];
#pragma unroll
    for (int e = 0; e < 4; e++)
#pragma unroll
        for (int jj = 0; jj < 8; jj++) rc[e][jj] = Rs[(lowbit*4 + e)*8 + jj];
    float bsc[4];
#pragma unroll
    for (int e = 0; e < 4; e++) bsc[e] = BSs[lowbit*4 + e];

#pragma unroll
    for (int i = 0; i < 4; i++) {
        int gmBase = m0 + wm + i*16 + kq*4;
#pragma unroll
        for (int j2 = 0; j2 < 4; j2++) {
            int gn = n0 + wn + j2*16 + lr;
            float br = b_route[gn];
            float own[4], oth[4];
#pragma unroll
            for (int e = 0; e < 4; e++) {
                own[e] = acc[i][j2][e];
                oth[e] = __shfl_xor(own[e], 16, 64);
            }
            float g8[8];
#pragma unroll
            for (int e = 0; e < 4; e++) {
                if (lowbit == 0) { g8[e] = own[e]; g8[4+e] = oth[e]; }
                else             { g8[e] = oth[e]; g8[4+e] = own[e]; }
            }
#pragma unroll
            for (int e = 0; e < 4; e++) {
                float m = 0.0f;
#pragma unroll
                for (int jj = 0; jj < 8; jj++) m += rc[e][jj] * g8[jj];
                m += bsc[e] * br;
                routed[(size_t)(gmBase + e) * H + gn] = f2bf(m);
            }
        }
    }
}

__global__ __launch_bounds__(256) void k_pass2(
    const float* __restrict__ x,
    const unsigned short* __restrict__ Wg,
    const float* __restrict__ b_gate,
    const unsigned short* __restrict__ routed,
    float* __restrict__ out)
{
    __shared__ unsigned short As[TM][LDApad];
    __shared__ unsigned short Bs[TM][LDApad];

    const int tid = threadIdx.x;
    const int bm = blockIdx.x >> 3;
    const int bn = blockIdx.x & 7;
    const int m0 = bm * TM;
    const int n0 = bn * TM;

    const int wid  = tid >> 6;
    const int lane = tid & 63;
    const int wm = (wid >> 1) * 64;
    const int wn = (wid & 1) * 64;
    const int lr = lane & 15;
    const int kq = lane >> 4;

    f32x4 acc[4][4];
#pragma unroll
    for (int i = 0; i < 4; i++)
#pragma unroll
        for (int j = 0; j < 4; j++) acc[i][j] = (f32x4)0.0f;

    for (int kt = 0; kt < H2 / BK; ++kt) {
        const int k0 = kt * BK;
        if (kt < H / BK) {
#pragma unroll
            for (int it = 0; it < 4; ++it) {
                int slot = it * 256 + tid;
                int r = slot >> 3, c8 = (slot & 7) * 8;
                const float* src = x + (size_t)(m0 + r) * H + k0 + c8;
                float4 v0 = *reinterpret_cast<const float4*>(src);
                float4 v1 = *reinterpret_cast<const float4*>(src + 4);
                short4v w0, w1;
                w0[0]=(short)f2bf(v0.x); w0[1]=(short)f2bf(v0.y); w0[2]=(short)f2bf(v0.z); w0[3]=(short)f2bf(v0.w);
                w1[0]=(short)f2bf(v1.x); w1[1]=(short)f2bf(v1.y); w1[2]=(short)f2bf(v1.z); w1[3]=(short)f2bf(v1.w);
                *reinterpret_cast<short4v*>(&As[r][c8])     = w0;
                *reinterpret_cast<short4v*>(&As[r][c8 + 4]) = w1;
            }
        } else {
#pragma unroll
            for (int it = 0; it < 4; ++it) {
                int slot = it * 256 + tid;
                int r = slot >> 3, c8 = (slot & 7) * 8;
                const unsigned short* src = routed + (size_t)(m0 + r) * H + (k0 - H) + c8;
                uint4 v = *reinterpret_cast<const uint4*>(src);
                *reinterpret_cast<uint2*>(&As[r][c8])     = make_uint2(v.x, v.y);
                *reinterpret_cast<uint2*>(&As[r][c8 + 4]) = make_uint2(v.z, v.w);
            }
        }
#pragma unroll
        for (int it = 0; it < 4; ++it) {
            int slot = it * 256 + tid;
            int r = slot >> 3, c8 = (slot & 7) * 8;
            const unsigned short* src = Wg + (size_t)(n0 + r) * H2 + k0 + c8;
            uint4 v = *reinterpret_cast<const uint4*>(src);
            *reinterpret_cast<uint2*>(&Bs[r][c8])     = make_uint2(v.x, v.y);
            *reinterpret_cast<uint2*>(&Bs[r][c8 + 4]) = make_uint2(v.z, v.w);
        }
        __syncthreads();
#pragma unroll
        for (int ks = 0; ks < BK; ks += 32) {
            short8 a[4], b[4];
#pragma unroll
            for (int i = 0; i < 4; i++) {
                frag_u fa;
                const unsigned short* pa = &As[wm + i*16 + lr][ks + kq*8];
                fa.p.lo = *reinterpret_cast<const short4v*>(pa);
                fa.p.hi = *reinterpret_cast<const short4v*>(pa + 4);
                a[i] = fa.s8;
            }
#pragma unroll
            for (int j = 0; j < 4; j++) {
                frag_u fb;
                const unsigned short* pb = &Bs[wn + j*16 + lr][ks + kq*8];
                fb.p.lo = *reinterpret_cast<const short4v*>(pb);
                fb.p.hi = *reinterpret_cast<const short4v*>(pb + 4);
                b[j] = fb.s8;
            }
#pragma unroll
            for (int i = 0; i < 4; i++)
#pragma unroll
                for (int j = 0; j < 4; j++)
                    acc[i][j] = __builtin_amdgcn_mfma_f32_16x16x32_bf16(a[i], b[j], acc[i][j], 0, 0, 0);
        }
        __syncthreads();
    }

#pragma unroll
    for (int i = 0; i < 4; i++) {
        int gmBase = m0 + wm + i*16 + kq*4;
#pragma unroll
        for (int j2 = 0; j2 < 4; j2++) {
            int gn = n0 + wn + j2*16 + lr;
            float bg = b_gate[gn];
#pragma unroll
            for (int e = 0; e < 4; e++) {
                size_t idx = (size_t)(gmBase + e) * H + gn;
                float t = acc[i][j2][e] + bg;
                float g = 1.0f / (1.0f + expf(-t));
                float rt = bf2f(routed[idx]);
                float xv = x[idx];
                out[idx] = g * rt + (1.0f - g) * xv;
            }
        }
    }
}

// ---------------- fallback (small ws): fully fused, fp32 vector ----------------
__global__ __launch_bounds__(256) void k_fallback(
    const float* __restrict__ x, const float* __restrict__ Wr, const float* __restrict__ br,
    const float* __restrict__ Wg, const float* __restrict__ bg,
    const float* __restrict__ wsR, const float* __restrict__ wsBS,
    float* __restrict__ out)
{
    __shared__ float xs[8][H];
    __shared__ float rt[8][H];
    __shared__ float Rs[64];
    __shared__ float BSs[8];

    const int tid = threadIdx.x;
    const size_t base = (size_t)blockIdx.x * (8 * H);
    if (tid < 64) Rs[tid] = wsR[tid];
    if (tid < 8)  BSs[tid] = wsBS[tid];

#pragma unroll
    for (int it = 0; it < 8; ++it) {
        int s = it * 256 + tid;
        reinterpret_cast<float4*>(&xs[0][0])[s] = reinterpret_cast<const float4*>(x + base)[s];
    }
    __syncthreads();

    for (int eo = 0; eo < 4; ++eo) {
        int e = eo * 256 + tid;
        float acc[8];
#pragma unroll
        for (int l = 0; l < 8; l++) acc[l] = 0.0f;
        const float* w = Wr + (size_t)e * H;
        for (int k = 0; k < H; k += 4) {
            float4 wv = *reinterpret_cast<const float4*>(w + k);
#pragma unroll
            for (int l = 0; l < 8; l++)
                acc[l] += wv.x * xs[l][k] + wv.y * xs[l][k+1] + wv.z * xs[l][k+2] + wv.w * xs[l][k+3];
        }
        float brv = br[e];
#pragma unroll
        for (int l = 0; l < 8; l++) {
            float m = 0.0f;
#pragma unroll
            for (int j = 0; j < 8; j++) m += Rs[l*8 + j] * acc[j];
            rt[l][e] = m + BSs[l] * brv;
        }
    }
    __syncthreads();

    for (int eo = 0; eo < 4; ++eo) {
        int e = eo * 256 + tid;
        float acc2[8];
#pragma unroll
        for (int l = 0; l < 8; l++) acc2[l] = 0.0f;
        const float* w1 = Wg + (size_t)e * (2 * H);
        for (int k = 0; k < H; k += 4) {
            float4 wv = *reinterpret_cast<const float4*>(w1 + k);
#pragma unroll
            for (int l = 0; l < 8; l++)
                acc2[l] += wv.x * xs[l][k] + wv.y * xs[l][k+1] + wv.z * xs[l][k+2] + wv.w * xs[l][k+3];
        }
        const float* w2 = w1 + H;
        for (int k = 0; k < H; k += 4) {
            float4 wv = *reinterpret_cast<const float4*>(w2 + k);
#pragma unroll
            for (int l = 0; l < 8; l++)
                acc2[l] += wv.x * rt[l][k] + wv.y * rt[l][k+1] + wv.z * rt[l][k+2] + wv.w * rt[l][k+3];
        }
        float bgv = bg[e];
#pragma unroll
        for (int l = 0; l < 8; l++) {
            float t = acc2[l] + bgv;
            float g = 1.0f / (1.0f + expf(-t));
            out[base + (size_t)l * H + e] = g * rt[l][e] + (1.0f - g) * xs[l][e];
        }
    }
}

extern "C" void kernel_launch(void* const* d_in, const int* in_sizes, int n_in,
                              void* d_out, int out_size, void* d_ws, size_t ws_size,
                              hipStream_t stream) {
    const float* x   = (const float*)d_in[0];
    const float* lp  = (const float*)d_in[1];
    const float* thr = (const float*)d_in[2];
    const float* Wr  = (const float*)d_in[3];
    const float* br  = (const float*)d_in[4];
    const float* Wg  = (const float*)d_in[5];
    const float* bg  = (const float*)d_in[6];
    float* out = (float*)d_out;
    char* ws = (char*)d_ws;

    float* wsR  = (float*)(ws + WS_R_OFF);
    float* wsBS = (float*)(ws + WS_BS_OFF);

    k_routing<<<1, 64, 0, stream>>>(lp, thr, wsR, wsBS);

    if (ws_size >= WS_NEED_FULL) {
        unsigned short* wsWr = (unsigned short*)(ws + WS_WR_OFF);
        unsigned short* wsWg = (unsigned short*)(ws + WS_WG_OFF);
        unsigned short* wsRt = (unsigned short*)(ws + WS_RT_OFF);
        unsigned short* wsXb = (unsigned short*)(ws + WS_XB_OFF);
        k_f32_to_bf16<<<512, 256, 0, stream>>>(Wr, wsWr, (1024 * 1024) / 4);
        k_f32_to_bf16<<<1024, 256, 0, stream>>>(Wg, wsWg, (1024 * 2048) / 4);
        k_f32_to_bf16<<<4096, 256, 0, stream>>>(x, wsXb, (MTOK * H) / 4);
        k_p1b<<<(MTOK / TM) * (H / TM), 256, 0, stream>>>(wsXb, wsWr, br, wsR, wsBS, wsRt);
        k_p2b<<<(MTOK / TM) * (H / TM), 256, 0, stream>>>(wsXb, wsWg, bg, wsRt, out);
    } else if (ws_size >= WS_NEED_MID) {
        unsigned short* wsWr = (unsigned short*)(ws + WS_WR_OFF);
        unsigned short* wsWg = (unsigned short*)(ws + WS_WG_OFF);
        unsigned short* wsRt = (unsigned short*)(ws + WS_RT_OFF);
        k_f32_to_bf16<<<512, 256, 0, stream>>>(Wr, wsWr, (1024 * 1024) / 4);
        k_f32_to_bf16<<<1024, 256, 0, stream>>>(Wg, wsWg, (1024 * 2048) / 4);
        k_pass1<<<(MTOK / TM) * (H / TM), 256, 0, stream>>>(x, wsWr, br, wsR, wsBS, wsRt);
        k_pass2<<<(MTOK / TM) * (H / TM), 256, 0, stream>>>(x, wsWg, bg, wsRt, out);
    } else {
        k_fallback<<<MTOK / 8, 256, 0, stream>>>(x, Wr, br, Wg, bg, wsR, wsBS, out);
    }
}

// Round 3
// 778.065 us; speedup vs baseline: 1.2182x; 1.0930x over previous
//
#include <hip/hip_runtime.h>
#include <math.h>

#define H 1024
#define H2 2048
#define MTOK 65536          // B*S*L = 4*2048*8
#define TM 128
#define BK 64
#define LDApad 72           // padded LDS row length (elems) -- mid-tier kernels only

typedef __attribute__((ext_vector_type(8))) short short8;
typedef __attribute__((ext_vector_type(4))) short short4v;
typedef __attribute__((ext_vector_type(4))) float f32x4;

union frag_u { short8 s8; struct { short4v lo, hi; } p; };

// ---------------- ws layout (bytes) ----------------
#define WS_R_OFF   0                          // 64 floats
#define WS_BS_OFF  256                        // 8 floats
#define WS_WR_OFF  4096                       // bf16 1024*1024   (2 MB)
#define WS_WG_OFF  (4096 + 2*1024*1024)       // bf16 1024*2048   (4 MB)
#define WS_RT_OFF  (8ull*1024*1024)           // bf16 MTOK*1024   (128 MB)
#define WS_XB_OFF  (WS_RT_OFF + (size_t)MTOK*H*2)   // bf16 MTOK*1024 (128 MB)
#define WS_NEED_FULL (WS_XB_OFF + (size_t)MTOK*H*2)
#define WS_NEED_MID  (WS_RT_OFF + (size_t)MTOK*H*2)

static __device__ __forceinline__ unsigned short f2bf(float f) {
    unsigned int u = __float_as_uint(f);
    u = u + 0x7fffu + ((u >> 16) & 1u);       // RNE
    return (unsigned short)(u >> 16);
}
static __device__ __forceinline__ float bf2f(unsigned short s) {
    return __uint_as_float(((unsigned int)s) << 16);
}

static __device__ __forceinline__ void gload16(const void* g, void* l) {
    __builtin_amdgcn_global_load_lds(
        (const __attribute__((address_space(1))) void*)g,
        (__attribute__((address_space(3))) void*)l, 16, 0, 0);
}

// ---------------- routing matrix ----------------
__global__ void k_routing(const float* __restrict__ lp, const float* __restrict__ thr,
                          float* __restrict__ wsR, float* __restrict__ wsBS) {
    int t = threadIdx.x;            // 0..63
    int i = t >> 3, j = t & 7;
    float mx = 0.5f * (lp[i*3+0] + lp[j*3+0]);
    float my = 0.5f * (lp[i*3+1] + lp[j*3+1]);
    float mz = 0.5f * (lp[i*3+2] + lp[j*3+2]);
    float f = sinf(mx)*cosf(my) + sinf(my)*cosf(mz) + sinf(mz)*cosf(mx) - thr[0];
    float r = 1.0f / (1.0f + expf(-2.0f * f));
    if (i == j) r = 1.0f;
    float s = r;
    s += __shfl_xor(s, 1, 64);
    s += __shfl_xor(s, 2, 64);
    s += __shfl_xor(s, 4, 64);
    float R = r / (s + 1e-6f);
    wsR[t] = R;
    if (j == 0) wsBS[i] = s / (s + 1e-6f);
}

// ---------------- fp32 -> bf16 convert ----------------
__global__ void k_f32_to_bf16(const float* __restrict__ src, unsigned short* __restrict__ dst, int n4) {
    int i = blockIdx.x * blockDim.x + threadIdx.x;
    int stride = gridDim.x * blockDim.x;
    for (; i < n4; i += stride) {
        float4 v = reinterpret_cast<const float4*>(src)[i];
        ushort4 o = make_ushort4(f2bf(v.x), f2bf(v.y), f2bf(v.z), f2bf(v.w));
        reinterpret_cast<ushort4*>(dst)[i] = o;
    }
}

// =====================================================================
// FAST TIER: all-bf16 GEMMs, m97 structure + T2 both-sides XOR swizzle
//   LDS[row][slot16B] = G[row][slot ^ (row&7)]  (linear LDS, pre-swizzled src)
//   read slot' = wanted_slot ^ (row&7)
// =====================================================================

// pass 1: routed = mix(xb @ Wr^T) + scale*b   (all-bf16 operands)
__global__ __launch_bounds__(256) void k_p1b(
    const unsigned short* __restrict__ xb,   // [MTOK][H] bf16
    const unsigned short* __restrict__ Wr,   // [H][H] bf16
    const float* __restrict__ b_route,
    const float* __restrict__ wsR, const float* __restrict__ wsBS,
    unsigned short* __restrict__ routed)
{
    __shared__ unsigned short As[TM * BK];   // linear [128][64]
    __shared__ unsigned short Bs[TM * BK];
    __shared__ float Rs[64];
    __shared__ float BSs[8];

    const int tid = threadIdx.x;
    // XCD-chunked bijective swizzle: nwg=4096, 512 per XCD
    const int l = (blockIdx.x & 7) * 512 + (blockIdx.x >> 3);
    const int bm = l >> 3;
    const int bn = l & 7;
    const int m0 = bm * TM;
    const int n0 = bn * TM;

    if (tid < 64) Rs[tid] = wsR[tid];
    if (tid < 8)  BSs[tid] = wsBS[tid];

    const int wid  = tid >> 6;
    const int lane = tid & 63;
    const int wm = (wid >> 1) * 64;
    const int wn = (wid & 1) * 64;
    const int lr = lane & 15;
    const int kq = lane >> 4;

    // staging geometry (per gload16: 64 lanes x 16B = 8 rows of 128B)
    const int lane8 = lane >> 3;            // row within 8-row group == row&7
    const int c8s   = ((lane & 7) ^ lane8) * 8;   // pre-swizzled 16B slot (elems)

    // read-side swizzle key: row&7 == lr&7 for both A and B fragments
    const int sw = lr & 7;

    f32x4 acc[4][4];
#pragma unroll
    for (int i = 0; i < 4; i++)
#pragma unroll
        for (int j = 0; j < 4; j++) acc[i][j] = (f32x4)0.0f;

    for (int kt = 0; kt < H / BK; ++kt) {
        const int k0 = kt * BK;
#pragma unroll
        for (int it = 0; it < 4; ++it) {
            const int sb = it * 4 + wid;         // 0..15, wave-uniform
            const int row = sb * 8 + lane8;
            gload16(xb + (size_t)(m0 + row) * H + k0 + c8s, &As[sb * 512]);
            gload16(Wr + (size_t)(n0 + row) * H + k0 + c8s, &Bs[sb * 512]);
        }
        __syncthreads();
#pragma unroll
        for (int ks = 0; ks < BK; ks += 32) {
            short8 a[4], b[4];
            const int slotw = (ks >> 3) + kq;    // wanted 16B slot
#pragma unroll
            for (int i = 0; i < 4; i++)
                a[i] = *reinterpret_cast<const short8*>(
                    &As[(wm + i*16 + lr) * BK + ((slotw ^ sw) << 3)]);
#pragma unroll
            for (int j = 0; j < 4; j++)
                b[j] = *reinterpret_cast<const short8*>(
                    &Bs[(wn + j*16 + lr) * BK + ((slotw ^ sw) << 3)]);
#pragma unroll
            for (int i = 0; i < 4; i++)
#pragma unroll
                for (int j = 0; j < 4; j++)
                    acc[i][j] = __builtin_amdgcn_mfma_f32_16x16x32_bf16(a[i], b[j], acc[i][j], 0, 0, 0);
        }
        __syncthreads();
    }

    // epilogue: limb mix (rows grouped by 8) + bias, store bf16
    const int lowbit = kq & 1;
    float rc[4][8];
#pragma unroll
    for (int e = 0; e < 4; e++)
#pragma unroll
        for (int jj = 0; jj < 8; jj++) rc[e][jj] = Rs[(lowbit*4 + e)*8 + jj];
    float bsc[4];
#pragma unroll
    for (int e = 0; e < 4; e++) bsc[e] = BSs[lowbit*4 + e];

#pragma unroll
    for (int i = 0; i < 4; i++) {
        int gmBase = m0 + wm + i*16 + kq*4;
#pragma unroll
        for (int j2 = 0; j2 < 4; j2++) {
            int gn = n0 + wn + j2*16 + lr;
            float br = b_route[gn];
            float own[4], oth[4];
#pragma unroll
            for (int e = 0; e < 4; e++) {
                own[e] = acc[i][j2][e];
                oth[e] = __shfl_xor(own[e], 16, 64);
            }
            float g8[8];
#pragma unroll
            for (int e = 0; e < 4; e++) {
                if (lowbit == 0) { g8[e] = own[e]; g8[4+e] = oth[e]; }
                else             { g8[e] = oth[e]; g8[4+e] = own[e]; }
            }
#pragma unroll
            for (int e = 0; e < 4; e++) {
                float m = 0.0f;
#pragma unroll
                for (int jj = 0; jj < 8; jj++) m += rc[e][jj] * g8[jj];
                m += bsc[e] * br;
                routed[(size_t)(gmBase + e) * H + gn] = f2bf(m);
            }
        }
    }
}

// pass 2: out = g*routed + (1-g)*x,  g = sigmoid([xb|routed] @ Wg^T + b)
__global__ __launch_bounds__(256) void k_p2b(
    const unsigned short* __restrict__ xb,     // [MTOK][H] bf16
    const unsigned short* __restrict__ Wg,     // [H][2H] bf16
    const float* __restrict__ b_gate,
    const unsigned short* __restrict__ routed, // [MTOK][H] bf16
    float* __restrict__ out)
{
    __shared__ unsigned short As[TM * BK];
    __shared__ unsigned short Bs[TM * BK];

    const int tid = threadIdx.x;
    const int l = (blockIdx.x & 7) * 512 + (blockIdx.x >> 3);
    const int bm = l >> 3;
    const int bn = l & 7;
    const int m0 = bm * TM;
    const int n0 = bn * TM;

    const int wid  = tid >> 6;
    const int lane = tid & 63;
    const int wm = (wid >> 1) * 64;
    const int wn = (wid & 1) * 64;
    const int lr = lane & 15;
    const int kq = lane >> 4;

    const int lane8 = lane >> 3;
    const int c8s   = ((lane & 7) ^ lane8) * 8;
    const int sw = lr & 7;

    f32x4 acc[4][4];
#pragma unroll
    for (int i = 0; i < 4; i++)
#pragma unroll
        for (int j = 0; j < 4; j++) acc[i][j] = (f32x4)0.0f;

    for (int kt = 0; kt < H2 / BK; ++kt) {
        const int k0 = kt * BK;
        const unsigned short* Asrc = (k0 < H) ? (xb + k0) : (routed + (k0 - H));
#pragma unroll
        for (int it = 0; it < 4; ++it) {
            const int sb = it * 4 + wid;
            const int row = sb * 8 + lane8;
            gload16(Asrc + (size_t)(m0 + row) * H + c8s, &As[sb * 512]);
            gload16(Wg + (size_t)(n0 + row) * H2 + k0 + c8s, &Bs[sb * 512]);
        }
        __syncthreads();
#pragma unroll
        for (int ks = 0; ks < BK; ks += 32) {
            short8 a[4], b[4];
            const int slotw = (ks >> 3) + kq;
#pragma unroll
            for (int i = 0; i < 4; i++)
                a[i] = *reinterpret_cast<const short8*>(
                    &As[(wm + i*16 + lr) * BK + ((slotw ^ sw) << 3)]);
#pragma unroll
            for (int j = 0; j < 4; j++)
                b[j] = *reinterpret_cast<const short8*>(
                    &Bs[(wn + j*16 + lr) * BK + ((slotw ^ sw) << 3)]);
#pragma unroll
            for (int i = 0; i < 4; i++)
#pragma unroll
                for (int j = 0; j < 4; j++)
                    acc[i][j] = __builtin_amdgcn_mfma_f32_16x16x32_bf16(a[i], b[j], acc[i][j], 0, 0, 0);
        }
        __syncthreads();
    }

    // epilogue: sigmoid gate + blend (bf16 x for blend -- error budget ok)
#pragma unroll
    for (int i = 0; i < 4; i++) {
        int gmBase = m0 + wm + i*16 + kq*4;
#pragma unroll
        for (int j2 = 0; j2 < 4; j2++) {
            int gn = n0 + wn + j2*16 + lr;
            float bg = b_gate[gn];
#pragma unroll
            for (int e = 0; e < 4; e++) {
                size_t idx = (size_t)(gmBase + e) * H + gn;
                float t = acc[i][j2][e] + bg;
                float g = 1.0f / (1.0f + expf(-t));
                float rt = bf2f(routed[idx]);
                float xv = bf2f(xb[idx]);
                out[idx] = g * rt + (1.0f - g) * xv;
            }
        }
    }
}

// =====================================================================
// MID TIER (ws >= 136 MB): Round-1 kernels (fp32 x staged+converted inline)
// =====================================================================

__global__ __launch_bounds__(256) void k_pass1(
    const float* __restrict__ x,
    const unsigned short* __restrict__ Wr,
    const float* __restrict__ b_route,
    const float* __restrict__ wsR,
    const float* __restrict__ wsBS,
    unsigned short* __restrict__ routed)
{
    __shared__ unsigned short As[TM][LDApad];
    __shared__ unsigned short Bs[TM][LDApad];
    __shared__ float Rs[64];
    __shared__ float BSs[8];

    const int tid = threadIdx.x;
    const int bm = blockIdx.x >> 3;
    const int bn = blockIdx.x & 7;
    const int m0 = bm * TM;
    const int n0 = bn * TM;

    if (tid < 64) Rs[tid] = wsR[tid];
    if (tid < 8)  BSs[tid] = wsBS[tid];

    const int wid  = tid >> 6;
    const int lane = tid & 63;
    const int wm = (wid >> 1) * 64;
    const int wn = (wid & 1) * 64;
    const int lr = lane & 15;
    const int kq = lane >> 4;

    f32x4 acc[4][4];
#pragma unroll
    for (int i = 0; i < 4; i++)
#pragma unroll
        for (int j = 0; j < 4; j++) acc[i][j] = (f32x4)0.0f;

    for (int kt = 0; kt < H / BK; ++kt) {
        const int k0 = kt * BK;
#pragma unroll
        for (int it = 0; it < 4; ++it) {
            int slot = it * 256 + tid;
            int r = slot >> 3, c8 = (slot & 7) * 8;
            const float* src = x + (size_t)(m0 + r) * H + k0 + c8;
            float4 v0 = *reinterpret_cast<const float4*>(src);
            float4 v1 = *reinterpret_cast<const float4*>(src + 4);
            short4v w0, w1;
            w0[0]=(short)f2bf(v0.x); w0[1]=(short)f2bf(v0.y); w0[2]=(short)f2bf(v0.z); w0[3]=(short)f2bf(v0.w);
            w1[0]=(short)f2bf(v1.x); w1[1]=(short)f2bf(v1.y); w1[2]=(short)f2bf(v1.z); w1[3]=(short)f2bf(v1.w);
            *reinterpret_cast<short4v*>(&As[r][c8])     = w0;
            *reinterpret_cast<short4v*>(&As[r][c8 + 4]) = w1;
        }
#pragma unroll
        for (int it = 0; it < 4; ++it) {
            int slot = it * 256 + tid;
            int r = slot >> 3, c8 = (slot & 7) * 8;
            const unsigned short* src = Wr + (size_t)(n0 + r) * H + k0 + c8;
            uint4 v = *reinterpret_cast<const uint4*>(src);
            *reinterpret_cast<uint2*>(&Bs[r][c8])     = make_uint2(v.x, v.y);
            *reinterpret_cast<uint2*>(&Bs[r][c8 + 4]) = make_uint2(v.z, v.w);
        }
        __syncthreads();
#pragma unroll
        for (int ks = 0; ks < BK; ks += 32) {
            short8 a[4], b[4];
#pragma unroll
            for (int i = 0; i < 4; i++) {
                frag_u fa;
                const unsigned short* pa = &As[wm + i*16 + lr][ks + kq*8];
                fa.p.lo = *reinterpret_cast<const short4v*>(pa);
                fa.p.hi = *reinterpret_cast<const short4v*>(pa + 4);
                a[i] = fa.s8;
            }
#pragma unroll
            for (int j = 0; j < 4; j++) {
                frag_u fb;
                const unsigned short* pb = &Bs[wn + j*16 + lr][ks + kq*8];
                fb.p.lo = *reinterpret_cast<const short4v*>(pb);
                fb.p.hi = *reinterpret_cast<const short4v*>(pb + 4);
                b[j] = fb.s8;
            }
#pragma unroll
            for (int i = 0; i < 4; i++)
#pragma unroll
                for (int j = 0; j < 4; j++)
                    acc[i][j] = __builtin_amdgcn_mfma_f32_16x16x32_bf16(a[i], b[j], acc[i][j], 0, 0, 0);
        }
        __syncthreads();
    }

    const int lowbit = kq & 1;
    float rc[4][8];
#pragma unroll
    for (int e = 0; e < 4; e++)
#pragma unroll
        for (int jj = 0; jj < 8; jj++) rc[e][jj] = Rs[(lowbit*4 + e)*8 + jj];
    float bsc[4];
#pragma unroll
    for (int e = 0; e < 4; e++) bsc[e] = BSs[lowbit*4 + e];

#pragma unroll
    for (int i = 0; i < 4; i++) {
        int gmBase = m0 + wm + i*16 + kq*4;
#pragma unroll
        for (int j2 = 0; j2 < 4; j2++) {
            int gn = n0 + wn + j2*16 + lr;
            float br = b_route[gn];
            float own[4], oth[4];
#pragma unroll
            for (int e = 0; e < 4; e++) {
                own[e] = acc[i][j2][e];
                oth[e] = __shfl_xor(own[e], 16, 64);
            }
            float g8[8];
#pragma unroll
            for (int e = 0; e < 4; e++) {
                if (lowbit == 0) { g8[e] = own[e]; g8[4+e] = oth[e]; }
                else             { g8[e] = oth[e]; g8[4+e] = own[e]; }
            }
#pragma unroll
            for (int e = 0; e < 4; e++) {
                float m = 0.0f;
#pragma unroll
                for (int jj = 0; jj < 8; jj++) m += rc[e][jj] * g8[jj];
                m += bsc[e] * br;
                routed[(size_t)(gmBase + e) * H + gn] = f2bf(m);
            }
        }
    }
}

__global__ __launch_bounds__(256) void k_pass2(
    const float* __restrict__ x,
    const unsigned short* __restrict__ Wg,
    const float* __restrict__ b_gate,
    const unsigned short* __restrict__ routed,
    float* __restrict__ out)
{
    __shared__ unsigned short As[TM][LDApad];
    __shared__ unsigned short Bs[TM][LDApad];

    const int tid = threadIdx.x;
    const int bm = blockIdx.x >> 3;
    const int bn = blockIdx.x & 7;
    const int m0 = bm * TM;
    const int n0 = bn * TM;

    const int wid  = tid >> 6;
    const int lane = tid & 63;
    const int wm = (wid >> 1) * 64;
    const int wn = (wid & 1) * 64;
    const int lr = lane & 15;
    const int kq = lane >> 4;

    f32x4 acc[4][4];
#pragma unroll
    for (int i = 0; i < 4; i++)
#pragma unroll
        for (int j = 0; j < 4; j++) acc[i][j] = (f32x4)0.0f;

    for (int kt = 0; kt < H2 / BK; ++kt) {
        const int k0 = kt * BK;
        if (kt < H / BK) {
#pragma unroll
            for (int it = 0; it < 4; ++it) {
                int slot = it * 256 + tid;
                int r = slot >> 3, c8 = (slot & 7) * 8;
                const float* src = x + (size_t)(m0 + r) * H + k0 + c8;
                float4 v0 = *reinterpret_cast<const float4*>(src);
                float4 v1 = *reinterpret_cast<const float4*>(src + 4);
                short4v w0, w1;
                w0[0]=(short)f2bf(v0.x); w0[1]=(short)f2bf(v0.y); w0[2]=(short)f2bf(v0.z); w0[3]=(short)f2bf(v0.w);
                w1[0]=(short)f2bf(v1.x); w1[1]=(short)f2bf(v1.y); w1[2]=(short)f2bf(v1.z); w1[3]=(short)f2bf(v1.w);
                *reinterpret_cast<short4v*>(&As[r][c8])     = w0;
                *reinterpret_cast<short4v*>(&As[r][c8 + 4]) = w1;
            }
        } else {
#pragma unroll
            for (int it = 0; it < 4; ++it) {
                int slot = it * 256 + tid;
                int r = slot >> 3, c8 = (slot & 7) * 8;
                const unsigned short* src = routed + (size_t)(m0 + r) * H + (k0 - H) + c8;
                uint4 v = *reinterpret_cast<const uint4*>(src);
                *reinterpret_cast<uint2*>(&As[r][c8])     = make_uint2(v.x, v.y);
                *reinterpret_cast<uint2*>(&As[r][c8 + 4]) = make_uint2(v.z, v.w);
            }
        }
#pragma unroll
        for (int it = 0; it < 4; ++it) {
            int slot = it * 256 + tid;
            int r = slot >> 3, c8 = (slot & 7) * 8;
            const unsigned short* src = Wg + (size_t)(n0 + r) * H2 + k0 + c8;
            uint4 v = *reinterpret_cast<const uint4*>(src);
            *reinterpret_cast<uint2*>(&Bs[r][c8])     = make_uint2(v.x, v.y);
            *reinterpret_cast<uint2*>(&Bs[r][c8 + 4]) = make_uint2(v.z, v.w);
        }
        __syncthreads();
#pragma unroll
        for (int ks = 0; ks < BK; ks += 32) {
            short8 a[4], b[4];
#pragma unroll
            for (int i = 0; i < 4; i++) {
                frag_u fa;
                const unsigned short* pa = &As[wm + i*16 + lr][ks + kq*8];
                fa.p.lo = *reinterpret_cast<const short4v*>(pa);
                fa.p.hi = *reinterpret_cast<const short4v*>(pa + 4);
                a[i] = fa.s8;
            }
#pragma unroll
            for (int j = 0; j < 4; j++) {
                frag_u fb;
                const unsigned short* pb = &Bs[wn + j*16 + lr][ks + kq*8];
                fb.p.lo = *reinterpret_cast<const short4v*>(pb);
                fb.p.hi = *reinterpret_cast<const short4v*>(pb + 4);
                b[j] = fb.s8;
            }
#pragma unroll
            for (int i = 0; i < 4; i++)
#pragma unroll
                for (int j = 0; j < 4; j++)
                    acc[i][j] = __builtin_amdgcn_mfma_f32_16x16x32_bf16(a[i], b[j], acc[i][j], 0, 0, 0);
        }
        __syncthreads();
    }

#pragma unroll
    for (int i = 0; i < 4; i++) {
        int gmBase = m0 + wm + i*16 + kq*4;
#pragma unroll
        for (int j2 = 0; j2 < 4; j2++) {
            int gn = n0 + wn + j2*16 + lr;
            float bg = b_gate[gn];
#pragma unroll
            for (int e = 0; e < 4; e++) {
                size_t idx = (size_t)(gmBase + e) * H + gn;
                float t = acc[i][j2][e] + bg;
                float g = 1.0f / (1.0f + expf(-t));
                float rt = bf2f(routed[idx]);
                float xv = x[idx];
                out[idx] = g * rt + (1.0f - g) * xv;
            }
        }
    }
}

// ---------------- fallback (small ws): fully fused, fp32 vector ----------------
__global__ __launch_bounds__(256) void k_fallback(
    const float* __restrict__ x, const float* __restrict__ Wr, const float* __restrict__ br,
    const float* __restrict__ Wg, const float* __restrict__ bg,
    const float* __restrict__ wsR, const float* __restrict__ wsBS,
    float* __restrict__ out)
{
    __shared__ float xs[8][H];
    __shared__ float rt[8][H];
    __shared__ float Rs[64];
    __shared__ float BSs[8];

    const int tid = threadIdx.x;
    const size_t base = (size_t)blockIdx.x * (8 * H);
    if (tid < 64) Rs[tid] = wsR[tid];
    if (tid < 8)  BSs[tid] = wsBS[tid];

#pragma unroll
    for (int it = 0; it < 8; ++it) {
        int s = it * 256 + tid;
        reinterpret_cast<float4*>(&xs[0][0])[s] = reinterpret_cast<const float4*>(x + base)[s];
    }
    __syncthreads();

    for (int eo = 0; eo < 4; ++eo) {
        int e = eo * 256 + tid;
        float acc[8];
#pragma unroll
        for (int l = 0; l < 8; l++) acc[l] = 0.0f;
        const float* w = Wr + (size_t)e * H;
        for (int k = 0; k < H; k += 4) {
            float4 wv = *reinterpret_cast<const float4*>(w + k);
#pragma unroll
            for (int l = 0; l < 8; l++)
                acc[l] += wv.x * xs[l][k] + wv.y * xs[l][k+1] + wv.z * xs[l][k+2] + wv.w * xs[l][k+3];
        }
        float brv = br[e];
#pragma unroll
        for (int l = 0; l < 8; l++) {
            float m = 0.0f;
#pragma unroll
            for (int j = 0; j < 8; j++) m += Rs[l*8 + j] * acc[j];
            rt[l][e] = m + BSs[l] * brv;
        }
    }
    __syncthreads();

    for (int eo = 0; eo < 4; ++eo) {
        int e = eo * 256 + tid;
        float acc2[8];
#pragma unroll
        for (int l = 0; l < 8; l++) acc2[l] = 0.0f;
        const float* w1 = Wg + (size_t)e * (2 * H);
        for (int k = 0; k < H; k += 4) {
            float4 wv = *reinterpret_cast<const float4*>(w1 + k);
#pragma unroll
            for (int l = 0; l < 8; l++)
                acc2[l] += wv.x * xs[l][k] + wv.y * xs[l][k+1] + wv.z * xs[l][k+2] + wv.w * xs[l][k+3];
        }
        const float* w2 = w1 + H;
        for (int k = 0; k < H; k += 4) {
            float4 wv = *reinterpret_cast<const float4*>(w2 + k);
#pragma unroll
            for (int l = 0; l < 8; l++)
                acc2[l] += wv.x * rt[l][k] + wv.y * rt[l][k+1] + wv.z * rt[l][k+2] + wv.w * rt[l][k+3];
        }
        float bgv = bg[e];
#pragma unroll
        for (int l = 0; l < 8; l++) {
            float t = acc2[l] + bgv;
            float g = 1.0f / (1.0f + expf(-t));
            out[base + (size_t)l * H + e] = g * rt[l][e] + (1.0f - g) * xs[l][e];
        }
    }
}

extern "C" void kernel_launch(void* const* d_in, const int* in_sizes, int n_in,
                              void* d_out, int out_size, void* d_ws, size_t ws_size,
                              hipStream_t stream) {
    const float* x   = (const float*)d_in[0];
    const float* lp  = (const float*)d_in[1];
    const float* thr = (const float*)d_in[2];
    const float* Wr  = (const float*)d_in[3];
    const float* br  = (const float*)d_in[4];
    const float* Wg  = (const float*)d_in[5];
    const float* bg  = (const float*)d_in[6];
    float* out = (float*)d_out;
    char* ws = (char*)d_ws;

    float* wsR  = (float*)(ws + WS_R_OFF);
    float* wsBS = (float*)(ws + WS_BS_OFF);

    k_routing<<<1, 64, 0, stream>>>(lp, thr, wsR, wsBS);

    if (ws_size >= WS_NEED_FULL) {
        unsigned short* wsWr = (unsigned short*)(ws + WS_WR_OFF);
        unsigned short* wsWg = (unsigned short*)(ws + WS_WG_OFF);
        unsigned short* wsRt = (unsigned short*)(ws + WS_RT_OFF);
        unsigned short* wsXb = (unsigned short*)(ws + WS_XB_OFF);
        k_f32_to_bf16<<<512, 256, 0, stream>>>(Wr, wsWr, (1024 * 1024) / 4);
        k_f32_to_bf16<<<1024, 256, 0, stream>>>(Wg, wsWg, (1024 * 2048) / 4);
        k_f32_to_bf16<<<4096, 256, 0, stream>>>(x, wsXb, (MTOK * H) / 4);
        k_p1b<<<(MTOK / TM) * (H / TM), 256, 0, stream>>>(wsXb, wsWr, br, wsR, wsBS, wsRt);
        k_p2b<<<(MTOK / TM) * (H / TM), 256, 0, stream>>>(wsXb, wsWg, bg, wsRt, out);
    } else if (ws_size >= WS_NEED_MID) {
        unsigned short* wsWr = (unsigned short*)(ws + WS_WR_OFF);
        unsigned short* wsWg = (unsigned short*)(ws + WS_WG_OFF);
        unsigned short* wsRt = (unsigned short*)(ws + WS_RT_OFF);
        k_f32_to_bf16<<<512, 256, 0, stream>>>(Wr, wsWr, (1024 * 1024) / 4);
        k_f32_to_bf16<<<1024, 256, 0, stream>>>(Wg, wsWg, (1024 * 2048) / 4);
        k_pass1<<<(MTOK / TM) * (H / TM), 256, 0, stream>>>(x, wsWr, br, wsR, wsBS, wsRt);
        k_pass2<<<(MTOK / TM) * (H / TM), 256, 0, stream>>>(x, wsWg, bg, wsRt, out);
    } else {
        k_fallback<<<MTOK / 8, 256, 0, stream>>>(x, Wr, br, Wg, bg, wsR, wsBS, out);
    }
}